// Round 1
// baseline (175.454 us; speedup 1.0000x reference)
//
#include <hip/hip_runtime.h>

typedef _Float16 f16;
typedef __attribute__((ext_vector_type(4))) _Float16 f16x4;
typedef __attribute__((ext_vector_type(8))) _Float16 f16x8;
typedef __attribute__((ext_vector_type(4))) float f32x4;

#define CEXP 0.18033688011112042f  /* 0.125 * log2(e) */

// ---------------- fp32 -> f16 convert (vectorized) ----------------
__global__ __launch_bounds__(256) void conv_f32_f16_k(const float* __restrict__ in,
                                                      f16* __restrict__ out) {
    int idx = (blockIdx.x * 256 + threadIdx.x) * 8;
    float4 a = *(const float4*)(in + idx);
    float4 b = *(const float4*)(in + idx + 4);
    f16x8 o;
    o[0] = (f16)a.x; o[1] = (f16)a.y; o[2] = (f16)a.z; o[3] = (f16)a.w;
    o[4] = (f16)b.x; o[5] = (f16)b.y; o[6] = (f16)b.z; o[7] = (f16)b.w;
    *(f16x8*)(out + idx) = o;
}

// ---- transpose + convert: out[(row_off+n)*ldo + k] = in[k*N + n] ----
__global__ __launch_bounds__(256) void transpose_conv_k(const float* __restrict__ in,
                                                        f16* __restrict__ out,
                                                        int N, int ldo, int row_off) {
    __shared__ float tile[32][33];
    int tx = threadIdx.x & 31, ty = threadIdx.x >> 5;  // 32 x 8
    int n0 = blockIdx.x * 32, k0 = blockIdx.y * 32;
#pragma unroll
    for (int j = 0; j < 4; j++)
        tile[ty + j * 8][tx] = in[(size_t)(k0 + ty + j * 8) * N + n0 + tx];
    __syncthreads();
#pragma unroll
    for (int j = 0; j < 4; j++)
        out[(size_t)(row_off + n0 + ty + j * 8) * ldo + k0 + tx] = (f16)tile[tx][ty + j * 8];
}

// ---------------- 128x128 f16 MFMA GEMM ----------------
// A [M][K] row-major f16; Bt [N][K] row-major f16 (i.e. B transposed).
// MODE 0: write f16 to Cqk (ld=1024) for col<1024, V-transposed to Cvt for col>=1024.
// MODE 1: write fp32 + bias to Cout (ld=1024).
template <int MODE>
__global__ __launch_bounds__(256) void gemm128_k(
    const f16* __restrict__ A, const f16* __restrict__ Bt,
    f16* __restrict__ Cqk, f16* __restrict__ Cvt,
    float* __restrict__ Cout, const float* __restrict__ bias,
    int K, int NTILES) {
    __shared__ __align__(16) f16 As[128 * 72];
    __shared__ __align__(16) f16 Bs[128 * 72];
    int bid = blockIdx.x;
    int nt = bid % NTILES, mt = bid / NTILES;
    int m0 = mt * 128, n0 = nt * 128;
    int tid = threadIdx.x;
    int lane = tid & 63, w = tid >> 6;
    int wm = w >> 1, wn = w & 1;
    int lr = lane & 15, lg = lane >> 4;
    f32x4 acc[4][4] = {};

    for (int k0 = 0; k0 < K; k0 += 64) {
#pragma unroll
        for (int i = 0; i < 4; i++) {
            int c = tid + i * 256;
            int row = c >> 3, kc = c & 7;
            uint4 va = *(const uint4*)(A + (size_t)(m0 + row) * K + k0 + kc * 8);
            uint4 vb = *(const uint4*)(Bt + (size_t)(n0 + row) * K + k0 + kc * 8);
            *(uint4*)(&As[row * 72 + kc * 8]) = va;
            *(uint4*)(&Bs[row * 72 + kc * 8]) = vb;
        }
        __syncthreads();
#pragma unroll
        for (int ks = 0; ks < 2; ks++) {
            f16x8 af[4], bf[4];
#pragma unroll
            for (int i = 0; i < 4; i++)
                af[i] = *(const f16x8*)(&As[(wm * 64 + i * 16 + lr) * 72 + ks * 32 + lg * 8]);
#pragma unroll
            for (int j = 0; j < 4; j++)
                bf[j] = *(const f16x8*)(&Bs[(wn * 64 + j * 16 + lr) * 72 + ks * 32 + lg * 8]);
#pragma unroll
            for (int i = 0; i < 4; i++)
#pragma unroll
                for (int j = 0; j < 4; j++)
                    acc[i][j] = __builtin_amdgcn_mfma_f32_16x16x32_f16(af[i], bf[j], acc[i][j], 0, 0, 0);
        }
        __syncthreads();
    }

#pragma unroll
    for (int i = 0; i < 4; i++) {
#pragma unroll
        for (int j = 0; j < 4; j++) {
            int row = m0 + wm * 64 + i * 16 + lg * 4;
            int col = n0 + wn * 64 + j * 16 + lr;
            if (MODE == 1) {
                float bv = bias[col];
#pragma unroll
                for (int r = 0; r < 4; r++)
                    Cout[(size_t)(row + r) * 1024 + col] = acc[i][j][r] + bv;
            } else {
                if (col < 1024) {
#pragma unroll
                    for (int r = 0; r < 4; r++)
                        Cqk[(size_t)(row + r) * 1024 + col] = (f16)acc[i][j][r];
                } else {
                    int c = col - 1024;
                    int hh = c >> 6, d = c & 63;
                    int bb = row >> 11, n = row & 2047;
                    f16x4 ov;
#pragma unroll
                    for (int r = 0; r < 4; r++) ov[r] = (f16)acc[i][j][r];
                    *(f16x4*)(Cvt + (size_t)((bb * 8 + hh) * 64 + d) * 2048 + n) = ov;
                }
            }
        }
    }
}

// ---------------- flash attention ----------------
// qkb [4096][1024] f16 : cols 0..511 Q, 512..1023 K (per token row)
// vt  [16][64][2048] f16: V transposed per (b,h) pair
// ao  [4096][512] f16  : attention output, token-major
// Trick: compute S^T = K*Q^T with mfma 16x16x16; its D layout equals the
// B-operand layout of the PV mfma, so P needs no cross-lane movement.
__global__ __launch_bounds__(256) void attn_k(const f16* __restrict__ qkb,
                                              const f16* __restrict__ vt,
                                              f16* __restrict__ ao) {
    int bid = blockIdx.x;
    int xcd = bid & 7, slot = bid >> 3;
    int pair = xcd * 2 + (slot >> 4);   // keep each pair's K/V on one XCD's L2
    int qt = slot & 15;
    int b = pair >> 3, h = pair & 7;
    int lane = threadIdx.x & 63, w = threadIdx.x >> 6;
    int lr = lane & 15, lg = lane >> 4;
    int q0 = qt * 128 + w * 32;

    const f16* qb = qkb + (size_t)b * 2048 * 1024 + h * 64;
    const f16* kb = qb + 512;
    const f16* vb = vt + (size_t)pair * 64 * 2048;

    f16x4 qf[2][4];
#pragma unroll
    for (int qg = 0; qg < 2; qg++)
#pragma unroll
        for (int dg = 0; dg < 4; dg++)
            qf[qg][dg] = *(const f16x4*)(qb + (size_t)(q0 + qg * 16 + lr) * 1024 + dg * 16 + lg * 4);

    f32x4 acc[4][2] = {};
    float m[2] = {-INFINITY, -INFINITY};
    float l[2] = {0.f, 0.f};

    for (int kv0 = 0; kv0 < 2048; kv0 += 64) {
        f16x4 kf[4][4];
#pragma unroll
        for (int kg = 0; kg < 4; kg++)
#pragma unroll
            for (int dg = 0; dg < 4; dg++)
                kf[kg][dg] = *(const f16x4*)(kb + (size_t)(kv0 + kg * 16 + lr) * 1024 + dg * 16 + lg * 4);

        f32x4 s[4][2] = {};
#pragma unroll
        for (int kg = 0; kg < 4; kg++)
#pragma unroll
            for (int qg = 0; qg < 2; qg++)
#pragma unroll
                for (int dg = 0; dg < 4; dg++)
                    s[kg][qg] = __builtin_amdgcn_mfma_f32_16x16x16f16(kf[kg][dg], qf[qg][dg], s[kg][qg], 0, 0, 0);

        f16x4 pf[4][2];
#pragma unroll
        for (int qg = 0; qg < 2; qg++) {
            float mx = -INFINITY;
#pragma unroll
            for (int kg = 0; kg < 4; kg++)
#pragma unroll
                for (int r = 0; r < 4; r++)
                    mx = fmaxf(mx, s[kg][qg][r]);
            mx = fmaxf(mx, __shfl_xor(mx, 16, 64));
            mx = fmaxf(mx, __shfl_xor(mx, 32, 64));
            float mn = fmaxf(m[qg], mx);
            float alpha = __builtin_amdgcn_exp2f((m[qg] - mn) * CEXP);
            m[qg] = mn;
            float rs = 0.f;
#pragma unroll
            for (int kg = 0; kg < 4; kg++) {
#pragma unroll
                for (int r = 0; r < 4; r++) {
                    float p = __builtin_amdgcn_exp2f((s[kg][qg][r] - mn) * CEXP);
                    rs += p;
                    pf[kg][qg][r] = (f16)p;
                }
            }
            rs += __shfl_xor(rs, 16, 64);
            rs += __shfl_xor(rs, 32, 64);
            l[qg] = l[qg] * alpha + rs;
#pragma unroll
            for (int dg = 0; dg < 4; dg++)
#pragma unroll
                for (int r = 0; r < 4; r++)
                    acc[dg][qg][r] *= alpha;
        }
#pragma unroll
        for (int kg = 0; kg < 4; kg++) {
#pragma unroll
            for (int dg = 0; dg < 4; dg++) {
                f16x4 vf = *(const f16x4*)(vb + (size_t)(dg * 16 + lr) * 2048 + kv0 + kg * 16 + lg * 4);
#pragma unroll
                for (int qg = 0; qg < 2; qg++)
                    acc[dg][qg] = __builtin_amdgcn_mfma_f32_16x16x16f16(vf, pf[kg][qg], acc[dg][qg], 0, 0, 0);
            }
        }
    }

#pragma unroll
    for (int qg = 0; qg < 2; qg++) {
        float inv = 1.f / l[qg];
#pragma unroll
        for (int dg = 0; dg < 4; dg++) {
            f16x4 ov;
#pragma unroll
            for (int r = 0; r < 4; r++) ov[r] = (f16)(acc[dg][qg][r] * inv);
            *(f16x4*)(ao + (size_t)(b * 2048 + q0 + qg * 16 + lr) * 512 + h * 64 + dg * 16 + lg * 4) = ov;
        }
    }
}

extern "C" void kernel_launch(void* const* d_in, const int* in_sizes, int n_in,
                              void* d_out, int out_size, void* d_ws, size_t ws_size,
                              hipStream_t stream) {
    const float* x   = (const float*)d_in[0];
    const float* Wq  = (const float*)d_in[1];
    const float* Wkv = (const float*)d_in[2];
    const float* Wo  = (const float*)d_in[3];
    const float* bo  = (const float*)d_in[4];
    float* out = (float*)d_out;

    // workspace layout (f16), total ~28 MB
    f16* xb    = (f16*)d_ws;                  // [4096][1024]
    f16* wqkvT = xb + 4096 * 1024;            // [1536][1024]
    f16* woT   = wqkvT + 1536 * 1024;         // [1024][512]
    f16* qkb   = woT + 1024 * 512;            // [4096][1024]  (Q | K)
    f16* vtb   = qkb + 4096 * 1024;           // [16][64][2048] V^T
    f16* ao    = vtb + 16 * 64 * 2048;        // [4096][512]

    conv_f32_f16_k<<<2048, 256, 0, stream>>>(x, xb);
    transpose_conv_k<<<dim3(16, 32), 256, 0, stream>>>(Wq, wqkvT, 512, 1024, 0);
    transpose_conv_k<<<dim3(32, 32), 256, 0, stream>>>(Wkv, wqkvT, 1024, 1024, 512);
    transpose_conv_k<<<dim3(32, 16), 256, 0, stream>>>(Wo, woT, 1024, 512, 0);

    gemm128_k<0><<<32 * 12, 256, 0, stream>>>(xb, wqkvT, qkb, vtb, nullptr, nullptr, 1024, 12);
    attn_k<<<256, 256, 0, stream>>>(qkb, vtb, ao);
    gemm128_k<1><<<32 * 8, 256, 0, stream>>>(ao, woT, nullptr, nullptr, out, bo, 512, 8);
}

// Round 2
// 147.386 us; speedup vs baseline: 1.1904x; 1.1904x over previous
//
#include <hip/hip_runtime.h>

typedef _Float16 f16;
typedef __attribute__((ext_vector_type(4))) _Float16 f16x4;
typedef __attribute__((ext_vector_type(8))) _Float16 f16x8;
typedef __attribute__((ext_vector_type(4))) float f32x4;

#define CEXP 0.18033688011112042f  /* 0.125 * log2(e) */

// ---------------- fp32 -> f16 convert (vectorized) ----------------
__global__ __launch_bounds__(256) void conv_f32_f16_k(const float* __restrict__ in,
                                                      f16* __restrict__ out) {
    int idx = (blockIdx.x * 256 + threadIdx.x) * 8;
    float4 a = *(const float4*)(in + idx);
    float4 b = *(const float4*)(in + idx + 4);
    f16x8 o;
    o[0] = (f16)a.x; o[1] = (f16)a.y; o[2] = (f16)a.z; o[3] = (f16)a.w;
    o[4] = (f16)b.x; o[5] = (f16)b.y; o[6] = (f16)b.z; o[7] = (f16)b.w;
    *(f16x8*)(out + idx) = o;
}

// ---- transpose + convert: out[(row_off+n)*ldo + k] = in[k*N + n] ----
__global__ __launch_bounds__(256) void transpose_conv_k(const float* __restrict__ in,
                                                        f16* __restrict__ out,
                                                        int N, int ldo, int row_off) {
    __shared__ float tile[32][33];
    int tx = threadIdx.x & 31, ty = threadIdx.x >> 5;  // 32 x 8
    int n0 = blockIdx.x * 32, k0 = blockIdx.y * 32;
#pragma unroll
    for (int j = 0; j < 4; j++)
        tile[ty + j * 8][tx] = in[(size_t)(k0 + ty + j * 8) * N + n0 + tx];
    __syncthreads();
#pragma unroll
    for (int j = 0; j < 4; j++)
        out[(size_t)(row_off + n0 + ty + j * 8) * ldo + k0 + tx] = (f16)tile[tx][ty + j * 8];
}

// ---------------- 128x128 f16 MFMA GEMM ----------------
template <int MODE>
__global__ __launch_bounds__(256) void gemm128_k(
    const f16* __restrict__ A, const f16* __restrict__ Bt,
    f16* __restrict__ Cqk, f16* __restrict__ Cvt,
    float* __restrict__ Cout, const float* __restrict__ bias,
    int K, int NTILES) {
    __shared__ __align__(16) f16 As[128 * 72];
    __shared__ __align__(16) f16 Bs[128 * 72];
    int bid = blockIdx.x;
    int nt = bid % NTILES, mt = bid / NTILES;
    int m0 = mt * 128, n0 = nt * 128;
    int tid = threadIdx.x;
    int lane = tid & 63, w = tid >> 6;
    int wm = w >> 1, wn = w & 1;
    int lr = lane & 15, lg = lane >> 4;
    f32x4 acc[4][4] = {};

    for (int k0 = 0; k0 < K; k0 += 64) {
#pragma unroll
        for (int i = 0; i < 4; i++) {
            int c = tid + i * 256;
            int row = c >> 3, kc = c & 7;
            uint4 va = *(const uint4*)(A + (size_t)(m0 + row) * K + k0 + kc * 8);
            uint4 vb = *(const uint4*)(Bt + (size_t)(n0 + row) * K + k0 + kc * 8);
            *(uint4*)(&As[row * 72 + kc * 8]) = va;
            *(uint4*)(&Bs[row * 72 + kc * 8]) = vb;
        }
        __syncthreads();
#pragma unroll
        for (int ks = 0; ks < 2; ks++) {
            f16x8 af[4], bf[4];
#pragma unroll
            for (int i = 0; i < 4; i++)
                af[i] = *(const f16x8*)(&As[(wm * 64 + i * 16 + lr) * 72 + ks * 32 + lg * 8]);
#pragma unroll
            for (int j = 0; j < 4; j++)
                bf[j] = *(const f16x8*)(&Bs[(wn * 64 + j * 16 + lr) * 72 + ks * 32 + lg * 8]);
#pragma unroll
            for (int i = 0; i < 4; i++)
#pragma unroll
                for (int j = 0; j < 4; j++)
                    acc[i][j] = __builtin_amdgcn_mfma_f32_16x16x32_f16(af[i], bf[j], acc[i][j], 0, 0, 0);
        }
        __syncthreads();
    }

#pragma unroll
    for (int i = 0; i < 4; i++) {
#pragma unroll
        for (int j = 0; j < 4; j++) {
            int row = m0 + wm * 64 + i * 16 + lg * 4;
            int col = n0 + wn * 64 + j * 16 + lr;
            if (MODE == 1) {
                float bv = bias[col];
#pragma unroll
                for (int r = 0; r < 4; r++)
                    Cout[(size_t)(row + r) * 1024 + col] = acc[i][j][r] + bv;
            } else {
                if (col < 1024) {
#pragma unroll
                    for (int r = 0; r < 4; r++)
                        Cqk[(size_t)(row + r) * 1024 + col] = (f16)acc[i][j][r];
                } else {
                    int c = col - 1024;
                    int hh = c >> 6, d = c & 63;
                    int bb = row >> 11, n = row & 2047;
                    f16x4 ov;
#pragma unroll
                    for (int r = 0; r < 4; r++) ov[r] = (f16)acc[i][j][r];
                    *(f16x4*)(Cvt + (size_t)((bb * 8 + hh) * 64 + d) * 2048 + n) = ov;
                }
            }
        }
    }
}

// ---------------- flash attention, KV-split x4 + LDS merge ----------------
// Each block: one (pair, 32 q-rows). Wave w handles kv range [w*512,(w+1)*512),
// partials (m, l, unnormalized O) merged through LDS at the end.
// S^T = K*Q^T via mfma 16x16x32 (D layout == PV's B-operand layout -> no shuffles).
__global__ __launch_bounds__(256, 4) void attn_k(const f16* __restrict__ qkb,
                                                 const f16* __restrict__ vt,
                                                 f16* __restrict__ ao) {
    __shared__ __align__(16) float accS[4][64][36];  // 36: pad to dodge 64-way bank conflict
    __shared__ float mS[4][2][16];
    __shared__ float lS[4][2][16];

    int bid = blockIdx.x;
    int xcd = bid & 7;
    int rest = bid >> 3;               // 0..127
    int pair = xcd * 2 + (rest & 1);   // each pair's K/V pinned to one XCD's L2
    int qblk = rest >> 1;              // 0..63
    int b = pair >> 3, h = pair & 7;
    int tid = threadIdx.x;
    int lane = tid & 63, w = tid >> 6;
    int lr = lane & 15, lg = lane >> 4;
    int q0 = qblk * 32;

    const f16* qb = qkb + (size_t)b * 2048 * 1024 + h * 64;
    const f16* kb = qb + 512;
    const f16* vb = vt + (size_t)pair * 64 * 2048;

    f16x8 qf[2][2];
#pragma unroll
    for (int qg = 0; qg < 2; qg++)
#pragma unroll
        for (int dg = 0; dg < 2; dg++)
            qf[qg][dg] = *(const f16x8*)(qb + (size_t)(q0 + qg * 16 + lr) * 1024 + dg * 32 + lg * 8);

    f32x4 acc[4][2] = {};
    float m[2] = {-INFINITY, -INFINITY};
    float l[2] = {0.f, 0.f};

    for (int t = 0; t < 8; t++) {
        int kv0 = w * 512 + t * 64;
        f32x4 s[4][2] = {};
#pragma unroll
        for (int kg = 0; kg < 4; kg++) {
            const f16* kr = kb + (size_t)(kv0 + kg * 16 + lr) * 1024 + lg * 8;
            f16x8 ka = *(const f16x8*)(kr);
            f16x8 kc = *(const f16x8*)(kr + 32);
#pragma unroll
            for (int qg = 0; qg < 2; qg++) {
                s[kg][qg] = __builtin_amdgcn_mfma_f32_16x16x32_f16(ka, qf[qg][0], s[kg][qg], 0, 0, 0);
                s[kg][qg] = __builtin_amdgcn_mfma_f32_16x16x32_f16(kc, qf[qg][1], s[kg][qg], 0, 0, 0);
            }
        }

        // V loads hoisted above softmax: latency hides under exp/rescale VALU
        f16x4 vf[4][4];
#pragma unroll
        for (int kg = 0; kg < 4; kg++)
#pragma unroll
            for (int dg = 0; dg < 4; dg++)
                vf[kg][dg] = *(const f16x4*)(vb + (size_t)(dg * 16 + lr) * 2048 + kv0 + kg * 16 + lg * 4);

        f16x4 pf[4][2];
#pragma unroll
        for (int qg = 0; qg < 2; qg++) {
            float mx = -INFINITY;
#pragma unroll
            for (int kg = 0; kg < 4; kg++)
#pragma unroll
                for (int r = 0; r < 4; r++)
                    mx = fmaxf(mx, s[kg][qg][r]);
            mx = fmaxf(mx, __shfl_xor(mx, 16, 64));
            mx = fmaxf(mx, __shfl_xor(mx, 32, 64));
            float mn = fmaxf(m[qg], mx);
            float alpha = __builtin_amdgcn_exp2f((m[qg] - mn) * CEXP);
            m[qg] = mn;
            float rs = 0.f;
#pragma unroll
            for (int kg = 0; kg < 4; kg++) {
#pragma unroll
                for (int r = 0; r < 4; r++) {
                    float p = __builtin_amdgcn_exp2f((s[kg][qg][r] - mn) * CEXP);
                    rs += p;
                    pf[kg][qg][r] = (f16)p;
                }
            }
            rs += __shfl_xor(rs, 16, 64);
            rs += __shfl_xor(rs, 32, 64);
            l[qg] = l[qg] * alpha + rs;
#pragma unroll
            for (int dg = 0; dg < 4; dg++)
#pragma unroll
                for (int r = 0; r < 4; r++)
                    acc[dg][qg][r] *= alpha;
        }

#pragma unroll
        for (int kg = 0; kg < 4; kg++)
#pragma unroll
            for (int dg = 0; dg < 4; dg++)
#pragma unroll
                for (int qg = 0; qg < 2; qg++)
                    acc[dg][qg] = __builtin_amdgcn_mfma_f32_16x16x16f16(vf[kg][dg], pf[kg][qg], acc[dg][qg], 0, 0, 0);
    }

    // ---- publish partials ----
#pragma unroll
    for (int dg = 0; dg < 4; dg++)
#pragma unroll
        for (int qg = 0; qg < 2; qg++)
            *(f32x4*)&accS[w][lane][(dg * 2 + qg) * 4] = acc[dg][qg];
    if (lg == 0) {
        mS[w][0][lr] = m[0]; mS[w][1][lr] = m[1];
        lS[w][0][lr] = l[0]; lS[w][1][lr] = l[1];
    }
    __syncthreads();

    // ---- merge: wave w owns output slice dg=w, qg=0..1 ----
#pragma unroll
    for (int qg = 0; qg < 2; qg++) {
        float mw[4];
        float M = -INFINITY;
#pragma unroll
        for (int w2 = 0; w2 < 4; w2++) {
            mw[w2] = mS[w2][qg][lr];
            M = fmaxf(M, mw[w2]);
        }
        f32x4 o = {};
        float L = 0.f;
#pragma unroll
        for (int w2 = 0; w2 < 4; w2++) {
            float sc = __builtin_amdgcn_exp2f((mw[w2] - M) * CEXP);
            f32x4 a = *(const f32x4*)&accS[w2][lane][(w * 2 + qg) * 4];
            o += a * sc;
            L += lS[w2][qg][lr] * sc;
        }
        float inv = 1.f / L;
        f16x4 ov;
#pragma unroll
        for (int r = 0; r < 4; r++) ov[r] = (f16)(o[r] * inv);
        *(f16x4*)(ao + (size_t)(b * 2048 + q0 + qg * 16 + lr) * 512 + h * 64 + w * 16 + lg * 4) = ov;
    }
}

extern "C" void kernel_launch(void* const* d_in, const int* in_sizes, int n_in,
                              void* d_out, int out_size, void* d_ws, size_t ws_size,
                              hipStream_t stream) {
    const float* x   = (const float*)d_in[0];
    const float* Wq  = (const float*)d_in[1];
    const float* Wkv = (const float*)d_in[2];
    const float* Wo  = (const float*)d_in[3];
    const float* bo  = (const float*)d_in[4];
    float* out = (float*)d_out;

    f16* xb    = (f16*)d_ws;                  // [4096][1024]
    f16* wqkvT = xb + 4096 * 1024;            // [1536][1024]
    f16* woT   = wqkvT + 1536 * 1024;         // [1024][512]
    f16* qkb   = woT + 1024 * 512;            // [4096][1024]  (Q | K)
    f16* vtb   = qkb + 4096 * 1024;           // [16][64][2048] V^T
    f16* ao    = vtb + 16 * 64 * 2048;        // [4096][512]

    conv_f32_f16_k<<<2048, 256, 0, stream>>>(x, xb);
    transpose_conv_k<<<dim3(16, 32), 256, 0, stream>>>(Wq, wqkvT, 512, 1024, 0);
    transpose_conv_k<<<dim3(32, 32), 256, 0, stream>>>(Wkv, wqkvT, 1024, 1024, 512);
    transpose_conv_k<<<dim3(32, 16), 256, 0, stream>>>(Wo, woT, 1024, 512, 0);

    gemm128_k<0><<<32 * 12, 256, 0, stream>>>(xb, wqkvT, qkb, vtb, nullptr, nullptr, 1024, 12);
    attn_k<<<1024, 256, 0, stream>>>(qkb, vtb, ao);
    gemm128_k<1><<<32 * 8, 256, 0, stream>>>(ao, woT, nullptr, nullptr, out, bo, 512, 8);
}

// Round 3
// 139.785 us; speedup vs baseline: 1.2552x; 1.0544x over previous
//
#include <hip/hip_runtime.h>

typedef _Float16 f16;
typedef __attribute__((ext_vector_type(4))) _Float16 f16x4;
typedef __attribute__((ext_vector_type(8))) _Float16 f16x8;
typedef __attribute__((ext_vector_type(4))) float f32x4;

#define CEXP 0.18033688011112042f  /* 0.125 * log2(e) */
#define QKB_LD 1056   /* 1024 + 32: 33 cache lines -> L2 channel spread */
#define VTB_LD 2080   /* 2048 + 32: 65 cache lines */

// ---------------- fp32 -> f16 convert (vectorized) ----------------
__global__ __launch_bounds__(256) void conv_f32_f16_k(const float* __restrict__ in,
                                                      f16* __restrict__ out) {
    int idx = (blockIdx.x * 256 + threadIdx.x) * 8;
    float4 a = *(const float4*)(in + idx);
    float4 b = *(const float4*)(in + idx + 4);
    f16x8 o;
    o[0] = (f16)a.x; o[1] = (f16)a.y; o[2] = (f16)a.z; o[3] = (f16)a.w;
    o[4] = (f16)b.x; o[5] = (f16)b.y; o[6] = (f16)b.z; o[7] = (f16)b.w;
    *(f16x8*)(out + idx) = o;
}

// ---- transpose + convert: out[(row_off+n)*ldo + k] = in[k*N + n] ----
__global__ __launch_bounds__(256) void transpose_conv_k(const float* __restrict__ in,
                                                        f16* __restrict__ out,
                                                        int N, int ldo, int row_off) {
    __shared__ float tile[32][33];
    int tx = threadIdx.x & 31, ty = threadIdx.x >> 5;  // 32 x 8
    int n0 = blockIdx.x * 32, k0 = blockIdx.y * 32;
#pragma unroll
    for (int j = 0; j < 4; j++)
        tile[ty + j * 8][tx] = in[(size_t)(k0 + ty + j * 8) * N + n0 + tx];
    __syncthreads();
#pragma unroll
    for (int j = 0; j < 4; j++)
        out[(size_t)(row_off + n0 + ty + j * 8) * ldo + k0 + tx] = (f16)tile[tx][ty + j * 8];
}

// ---------------- 128x128 f16 MFMA GEMM ----------------
template <int MODE>
__global__ __launch_bounds__(256) void gemm128_k(
    const f16* __restrict__ A, const f16* __restrict__ Bt,
    f16* __restrict__ Cqk, f16* __restrict__ Cvt,
    float* __restrict__ Cout, const float* __restrict__ bias,
    int K, int NTILES) {
    __shared__ __align__(16) f16 As[128 * 72];
    __shared__ __align__(16) f16 Bs[128 * 72];
    int bid = blockIdx.x;
    int nt = bid % NTILES, mt = bid / NTILES;
    int m0 = mt * 128, n0 = nt * 128;
    int tid = threadIdx.x;
    int lane = tid & 63, w = tid >> 6;
    int wm = w >> 1, wn = w & 1;
    int lr = lane & 15, lg = lane >> 4;
    f32x4 acc[4][4] = {};

    for (int k0 = 0; k0 < K; k0 += 64) {
#pragma unroll
        for (int i = 0; i < 4; i++) {
            int c = tid + i * 256;
            int row = c >> 3, kc = c & 7;
            uint4 va = *(const uint4*)(A + (size_t)(m0 + row) * K + k0 + kc * 8);
            uint4 vb = *(const uint4*)(Bt + (size_t)(n0 + row) * K + k0 + kc * 8);
            *(uint4*)(&As[row * 72 + kc * 8]) = va;
            *(uint4*)(&Bs[row * 72 + kc * 8]) = vb;
        }
        __syncthreads();
#pragma unroll
        for (int ks = 0; ks < 2; ks++) {
            f16x8 af[4], bf[4];
#pragma unroll
            for (int i = 0; i < 4; i++)
                af[i] = *(const f16x8*)(&As[(wm * 64 + i * 16 + lr) * 72 + ks * 32 + lg * 8]);
#pragma unroll
            for (int j = 0; j < 4; j++)
                bf[j] = *(const f16x8*)(&Bs[(wn * 64 + j * 16 + lr) * 72 + ks * 32 + lg * 8]);
#pragma unroll
            for (int i = 0; i < 4; i++)
#pragma unroll
                for (int j = 0; j < 4; j++)
                    acc[i][j] = __builtin_amdgcn_mfma_f32_16x16x32_f16(af[i], bf[j], acc[i][j], 0, 0, 0);
        }
        __syncthreads();
    }

#pragma unroll
    for (int i = 0; i < 4; i++) {
#pragma unroll
        for (int j = 0; j < 4; j++) {
            int row = m0 + wm * 64 + i * 16 + lg * 4;
            int col = n0 + wn * 64 + j * 16 + lr;
            if (MODE == 1) {
                float bv = bias[col];
#pragma unroll
                for (int r = 0; r < 4; r++)
                    Cout[(size_t)(row + r) * 1024 + col] = acc[i][j][r] + bv;
            } else {
                if (col < 1024) {
#pragma unroll
                    for (int r = 0; r < 4; r++)
                        Cqk[(size_t)(row + r) * QKB_LD + col] = (f16)acc[i][j][r];
                } else {
                    int c = col - 1024;
                    int hh = c >> 6, d = c & 63;
                    int bb = row >> 11, n = row & 2047;
                    f16x4 ov;
#pragma unroll
                    for (int r = 0; r < 4; r++) ov[r] = (f16)acc[i][j][r];
                    *(f16x4*)(Cvt + (size_t)((bb * 8 + hh) * 64 + d) * VTB_LD + n) = ov;
                }
            }
        }
    }
}

// ---------------- flash attention: LDS-staged KV, double-buffered ----------------
// Block = 4 waves, QBLK=64 (16 q-rows/wave), KVBLK=128 shared via LDS.
// Reg-staged global->LDS: issue loads early, ds_write after compute (T14),
// one barrier per iter (writes target the buffer nobody reads this iter).
// S^T = K*Q^T (D layout == PV B-operand layout -> zero shuffles).
__global__ __launch_bounds__(256, 2) void attn_k(const f16* __restrict__ qkb,
                                                 const f16* __restrict__ vt,
                                                 f16* __restrict__ ao) {
    __shared__ __align__(16) f16 Ks[2][128][72];   // 36,864 B  (pad 64->72)
    __shared__ __align__(16) f16 Vs[2][64][136];   // 34,816 B  (pad 128->136)

    int bid = blockIdx.x;
    int xcd = bid & 7;
    int pair = xcd * 2 + ((bid >> 3) & 1);  // pin each pair's K/V to one XCD L2
    int qblk = bid >> 4;                    // 0..31
    int b = pair >> 3, h = pair & 7;
    int tid = threadIdx.x;
    int lane = tid & 63, w = tid >> 6;
    int lr = lane & 15, lg = lane >> 4;
    int q0 = qblk * 64 + w * 16;

    const f16* qb = qkb + (size_t)b * 2048 * QKB_LD + h * 64;
    const f16* kb = qb + 512;
    const f16* vb = vt + (size_t)pair * 64 * VTB_LD;

    // Q fragments (held in registers for the whole kernel)
    f16x8 qf0 = *(const f16x8*)(qb + (size_t)(q0 + lr) * QKB_LD + lg * 8);
    f16x8 qf1 = *(const f16x8*)(qb + (size_t)(q0 + lr) * QKB_LD + 32 + lg * 8);

    // staging geometry: K chunk = 32 rows x 64 cols, V chunk = 16 rows x 128 cols
    int kr = tid >> 3, kc = (tid & 7) * 8;
    int vd = tid >> 4, vc = (tid & 15) * 8;

    uint4 kreg[4], vreg[4];
#pragma unroll
    for (int j = 0; j < 4; j++) {
        kreg[j] = *(const uint4*)(kb + (size_t)(j * 32 + kr) * QKB_LD + kc);
        vreg[j] = *(const uint4*)(vb + (size_t)(j * 16 + vd) * VTB_LD + vc);
    }
#pragma unroll
    for (int j = 0; j < 4; j++) {
        *(uint4*)(&Ks[0][j * 32 + kr][kc]) = kreg[j];
        *(uint4*)(&Vs[0][j * 16 + vd][vc]) = vreg[j];
    }
    __syncthreads();

    f32x4 acc[4] = {};
    float m = -INFINITY, l = 0.f;

    for (int t = 0; t < 16; t++) {
        int cur = t & 1;
        // issue next tile's global loads (latency hides under compute)
        if (t < 15) {
            int kv1 = (t + 1) * 128;
#pragma unroll
            for (int j = 0; j < 4; j++) {
                kreg[j] = *(const uint4*)(kb + (size_t)(kv1 + j * 32 + kr) * QKB_LD + kc);
                vreg[j] = *(const uint4*)(vb + (size_t)(j * 16 + vd) * VTB_LD + kv1 + vc);
            }
        }

        // ---- QK^T (S^T tile [128 kv][16 q] per wave) ----
        f32x4 s[8];
#pragma unroll
        for (int kg = 0; kg < 8; kg++) {
            f16x8 ka0 = *(const f16x8*)(&Ks[cur][kg * 16 + lr][lg * 8]);
            f16x8 ka1 = *(const f16x8*)(&Ks[cur][kg * 16 + lr][32 + lg * 8]);
            f32x4 z = {};
            z = __builtin_amdgcn_mfma_f32_16x16x32_f16(ka0, qf0, z, 0, 0, 0);
            s[kg] = __builtin_amdgcn_mfma_f32_16x16x32_f16(ka1, qf1, z, 0, 0, 0);
        }

        // ---- online softmax (per q-col: 32 in-lane values + 4-group cross-lane) ----
        float mx = -INFINITY;
#pragma unroll
        for (int kg = 0; kg < 8; kg++)
#pragma unroll
            for (int r = 0; r < 4; r++)
                mx = fmaxf(mx, s[kg][r]);
        mx = fmaxf(mx, __shfl_xor(mx, 16, 64));
        mx = fmaxf(mx, __shfl_xor(mx, 32, 64));
        float mn = fmaxf(m, mx);
        float alpha = __builtin_amdgcn_exp2f((m - mn) * CEXP);
        m = mn;
        float rs = 0.f;
        f16x4 pf[8];
#pragma unroll
        for (int kg = 0; kg < 8; kg++)
#pragma unroll
            for (int r = 0; r < 4; r++) {
                float p = __builtin_amdgcn_exp2f((s[kg][r] - mn) * CEXP);
                rs += p;
                pf[kg][r] = (f16)p;
            }
        rs += __shfl_xor(rs, 16, 64);
        rs += __shfl_xor(rs, 32, 64);
        l = l * alpha + rs;
#pragma unroll
        for (int dg = 0; dg < 4; dg++)
#pragma unroll
            for (int r = 0; r < 4; r++)
                acc[dg][r] *= alpha;

        // ---- PV: acc[dg] += V^T frag x P frag ----
#pragma unroll
        for (int kg = 0; kg < 8; kg++)
#pragma unroll
            for (int dg = 0; dg < 4; dg++) {
                f16x4 vf = *(const f16x4*)(&Vs[cur][dg * 16 + lr][kg * 16 + lg * 4]);
                acc[dg] = __builtin_amdgcn_mfma_f32_16x16x16f16(vf, pf[kg], acc[dg], 0, 0, 0);
            }

        // ---- write next tile to the other buffer (vmcnt auto-inserted) ----
        if (t < 15) {
            int nxt = cur ^ 1;
#pragma unroll
            for (int j = 0; j < 4; j++) {
                *(uint4*)(&Ks[nxt][j * 32 + kr][kc]) = kreg[j];
                *(uint4*)(&Vs[nxt][j * 16 + vd][vc]) = vreg[j];
            }
        }
        __syncthreads();
    }

    float inv = 1.f / l;
#pragma unroll
    for (int dg = 0; dg < 4; dg++) {
        f16x4 ov;
#pragma unroll
        for (int r = 0; r < 4; r++) ov[r] = (f16)(acc[dg][r] * inv);
        *(f16x4*)(ao + (size_t)(b * 2048 + q0 + lr) * 512 + h * 64 + dg * 16 + lg * 4) = ov;
    }
}

extern "C" void kernel_launch(void* const* d_in, const int* in_sizes, int n_in,
                              void* d_out, int out_size, void* d_ws, size_t ws_size,
                              hipStream_t stream) {
    const float* x   = (const float*)d_in[0];
    const float* Wq  = (const float*)d_in[1];
    const float* Wkv = (const float*)d_in[2];
    const float* Wo  = (const float*)d_in[3];
    const float* bo  = (const float*)d_in[4];
    float* out = (float*)d_out;

    f16* xb    = (f16*)d_ws;                  // [4096][1024]
    f16* wqkvT = xb + 4096 * 1024;            // [1536][1024]
    f16* woT   = wqkvT + 1536 * 1024;         // [1024][512]
    f16* qkb   = woT + 1024 * 512;            // [4096][QKB_LD]  (Q | K, padded)
    f16* vtb   = qkb + 4096 * QKB_LD;         // [16][64][VTB_LD] V^T (padded)
    f16* ao    = vtb + 16 * 64 * VTB_LD;      // [4096][512]

    conv_f32_f16_k<<<2048, 256, 0, stream>>>(x, xb);
    transpose_conv_k<<<dim3(16, 32), 256, 0, stream>>>(Wq, wqkvT, 512, 1024, 0);
    transpose_conv_k<<<dim3(32, 32), 256, 0, stream>>>(Wkv, wqkvT, 1024, 1024, 512);
    transpose_conv_k<<<dim3(32, 16), 256, 0, stream>>>(Wo, woT, 1024, 512, 0);

    gemm128_k<0><<<32 * 12, 256, 0, stream>>>(xb, wqkvT, qkb, vtb, nullptr, nullptr, 1024, 12);
    attn_k<<<512, 256, 0, stream>>>(qkb, vtb, ao);
    gemm128_k<1><<<32 * 8, 256, 0, stream>>>(ao, woT, nullptr, nullptr, out, bo, 512, 8);
}

// Round 4
// 94.701 us; speedup vs baseline: 1.8527x; 1.4761x over previous
//
#include <hip/hip_runtime.h>

typedef _Float16 f16;
typedef __attribute__((ext_vector_type(4))) _Float16 f16x4;
typedef __attribute__((ext_vector_type(8))) _Float16 f16x8;
typedef __attribute__((ext_vector_type(4))) float f32x4;

#define CEXP 0.18033688011112042f  /* 0.125 * log2(e) */
#define QKB_LD 1056   /* 1024 + 32: 33 cache lines -> L2 channel spread */
#define VTB_LD 2080   /* 2048 + 32 */

__device__ __forceinline__ void gload16(const f16* g, f16* l) {
    __builtin_amdgcn_global_load_lds((const __attribute__((address_space(1))) void*)g,
                                     (__attribute__((address_space(3))) void*)l, 16, 0, 0);
}

// ---------------- fp32 -> f16 convert (vectorized) ----------------
__global__ __launch_bounds__(256) void conv_f32_f16_k(const float* __restrict__ in,
                                                      f16* __restrict__ out) {
    int idx = (blockIdx.x * 256 + threadIdx.x) * 8;
    float4 a = *(const float4*)(in + idx);
    float4 b = *(const float4*)(in + idx + 4);
    f16x8 o;
    o[0] = (f16)a.x; o[1] = (f16)a.y; o[2] = (f16)a.z; o[3] = (f16)a.w;
    o[4] = (f16)b.x; o[5] = (f16)b.y; o[6] = (f16)b.z; o[7] = (f16)b.w;
    *(f16x8*)(out + idx) = o;
}

// ---- transpose + convert: out[(row_off+n)*ldo + k] = in[k*N + n] ----
__global__ __launch_bounds__(256) void transpose_conv_k(const float* __restrict__ in,
                                                        f16* __restrict__ out,
                                                        int N, int ldo, int row_off) {
    __shared__ float tile[32][33];
    int tx = threadIdx.x & 31, ty = threadIdx.x >> 5;  // 32 x 8
    int n0 = blockIdx.x * 32, k0 = blockIdx.y * 32;
#pragma unroll
    for (int j = 0; j < 4; j++)
        tile[ty + j * 8][tx] = in[(size_t)(k0 + ty + j * 8) * N + n0 + tx];
    __syncthreads();
#pragma unroll
    for (int j = 0; j < 4; j++)
        out[(size_t)(row_off + n0 + ty + j * 8) * ldo + k0 + tx] = (f16)tile[tx][ty + j * 8];
}

// ---------------- 128x128 f16 MFMA GEMM ----------------
template <int MODE>
__global__ __launch_bounds__(256) void gemm128_k(
    const f16* __restrict__ A, const f16* __restrict__ Bt,
    f16* __restrict__ Cqk, f16* __restrict__ Cvt,
    float* __restrict__ Cout, const float* __restrict__ bias,
    int K, int NTILES) {
    __shared__ __align__(16) f16 As[128 * 72];
    __shared__ __align__(16) f16 Bs[128 * 72];
    int bid = blockIdx.x;
    int nt = bid % NTILES, mt = bid / NTILES;
    int m0 = mt * 128, n0 = nt * 128;
    int tid = threadIdx.x;
    int lane = tid & 63, w = tid >> 6;
    int wm = w >> 1, wn = w & 1;
    int lr = lane & 15, lg = lane >> 4;
    f32x4 acc[4][4] = {};

    for (int k0 = 0; k0 < K; k0 += 64) {
#pragma unroll
        for (int i = 0; i < 4; i++) {
            int c = tid + i * 256;
            int row = c >> 3, kc = c & 7;
            uint4 va = *(const uint4*)(A + (size_t)(m0 + row) * K + k0 + kc * 8);
            uint4 vb = *(const uint4*)(Bt + (size_t)(n0 + row) * K + k0 + kc * 8);
            *(uint4*)(&As[row * 72 + kc * 8]) = va;
            *(uint4*)(&Bs[row * 72 + kc * 8]) = vb;
        }
        __syncthreads();
#pragma unroll
        for (int ks = 0; ks < 2; ks++) {
            f16x8 af[4], bf[4];
#pragma unroll
            for (int i = 0; i < 4; i++)
                af[i] = *(const f16x8*)(&As[(wm * 64 + i * 16 + lr) * 72 + ks * 32 + lg * 8]);
#pragma unroll
            for (int j = 0; j < 4; j++)
                bf[j] = *(const f16x8*)(&Bs[(wn * 64 + j * 16 + lr) * 72 + ks * 32 + lg * 8]);
#pragma unroll
            for (int i = 0; i < 4; i++)
#pragma unroll
                for (int j = 0; j < 4; j++)
                    acc[i][j] = __builtin_amdgcn_mfma_f32_16x16x32_f16(af[i], bf[j], acc[i][j], 0, 0, 0);
        }
        __syncthreads();
    }

#pragma unroll
    for (int i = 0; i < 4; i++) {
#pragma unroll
        for (int j = 0; j < 4; j++) {
            int row = m0 + wm * 64 + i * 16 + lg * 4;
            int col = n0 + wn * 64 + j * 16 + lr;
            if (MODE == 1) {
                float bv = bias[col];
#pragma unroll
                for (int r = 0; r < 4; r++)
                    Cout[(size_t)(row + r) * 1024 + col] = acc[i][j][r] + bv;
            } else {
                if (col < 1024) {
#pragma unroll
                    for (int r = 0; r < 4; r++)
                        Cqk[(size_t)(row + r) * QKB_LD + col] = (f16)acc[i][j][r];
                } else {
                    int c = col - 1024;
                    int hh = c >> 6, d = c & 63;
                    int bb = row >> 11, n = row & 2047;
                    f16x4 ov;
#pragma unroll
                    for (int r = 0; r < 4; r++) ov[r] = (f16)acc[i][j][r];
                    *(f16x4*)(Cvt + (size_t)((bb * 8 + hh) * 64 + d) * VTB_LD + n) = ov;
                }
            }
        }
    }
}

// ---------------- flash attention: global_load_lds staged KV ----------------
// Block = 4 waves, QBLK=64 (16 q-rows/wave), KVBLK=128 shared via LDS.
// Zero staging VGPRs (global_load_lds, 16B/lane), double-buffered, one
// barrier/iter. LDS unpadded with both-sides XOR swizzle (rule #21):
// physE = colE ^ ((row&7)<<3); source address pre-swizzled, read swizzled.
// S^T = K*Q^T (D layout == PV B-operand layout -> zero shuffles).
__global__ __launch_bounds__(256, 2) void attn_k(const f16* __restrict__ qkb,
                                                 const f16* __restrict__ vt,
                                                 f16* __restrict__ ao) {
    __shared__ __align__(16) f16 Ks[2][128 * 64];   // 16 KB each
    __shared__ __align__(16) f16 Vs[2][64 * 128];   // 16 KB each

    int bid = blockIdx.x;
    int xcd = bid & 7;
    int pair = xcd * 2 + ((bid >> 3) & 1);  // pin each pair's K/V to one XCD L2
    int qblk = bid >> 4;                    // 0..31
    int b = pair >> 3, h = pair & 7;
    int tid = threadIdx.x;
    int lane = tid & 63, w = tid >> 6;
    int lr = lane & 15, lg = lane >> 4;
    int q0 = qblk * 64 + w * 16;

    const f16* qb = qkb + (size_t)b * 2048 * QKB_LD + h * 64;
    const f16* kb = qb + 512;
    const f16* vb = vt + (size_t)pair * 64 * VTB_LD;

    // Q fragments (registers for whole kernel)
    f16x8 qf0 = *(const f16x8*)(qb + (size_t)(q0 + lr) * QKB_LD + lg * 8);
    f16x8 qf1 = *(const f16x8*)(qb + (size_t)(q0 + lr) * QKB_LD + 32 + lg * 8);

    // ---- staging geometry (per-lane source offsets, inverse-swizzled) ----
    // K: call j stages rows [w*32+j*8, +8); lane covers row w*32+j*8+(l>>3),
    //    16B chunk (l&7). Logical colE for linear pos = ((l&7)*8) ^ ((row&7)<<3),
    //    row&7 == l>>3 (j*8, w*32 are multiples of 8).
    int kColSrc = ((lane & 7) * 8) ^ ((lane >> 3) << 3);
    int kRowL = (lane >> 3);  // 0..7
    // V: call j stages rows [w*16+j*4, +4); lane covers row w*16+j*4+(l>>4),
    //    chunk (l&15). row&7 = (l>>4) + 4*(j&1)  (disjoint bits -> XOR form).
    int vColSrc = ((lane & 15) * 8) ^ ((lane >> 4) << 3);  // ^ ((j&1)<<5) per call
    int vRowL = (lane >> 4);  // 0..3

    // ---- read-side swizzled offsets ----
    int kOffA = (lg * 8) ^ ((lr & 7) << 3);          // QK: +kg*16*64 row step, ^32 for hi half
    int vOffL = (lg * 4) ^ ((lr & 7) << 3);          // PV: ^ (kg<<4), + (dg*16+lr)*128

    // ---- stage tile 0 into buf 0 ----
    {
        const f16* ksrc = kb + (size_t)(w * 32 + kRowL) * QKB_LD + kColSrc;
        const f16* vsrc = vb + (size_t)(w * 16 + vRowL) * VTB_LD + vColSrc;
#pragma unroll
        for (int j = 0; j < 4; j++) {
            gload16(ksrc + (size_t)j * 8 * QKB_LD, &Ks[0][(w * 32 + j * 8) * 64]);
            gload16(vsrc + (size_t)(j * 4) * VTB_LD + ((j & 1) << 5) - (((j & 1) << 5) & vColSrc) * 2,
                    &Vs[0][(w * 16 + j * 4) * 128]);
        }
    }
    __syncthreads();

    f32x4 acc[4] = {};
    float m = -INFINITY, l = 0.f;

    for (int t = 0; t < 16; t++) {
        int cur = t & 1;
        // ---- issue next tile's loads (async, drains at end-of-iter barrier) ----
        if (t < 15) {
            int kv1 = (t + 1) * 128;
            int nxt = cur ^ 1;
            const f16* ksrc = kb + (size_t)(kv1 + w * 32 + kRowL) * QKB_LD + kColSrc;
            const f16* vsrc0 = vb + (size_t)(w * 16 + vRowL) * VTB_LD + kv1;
#pragma unroll
            for (int j = 0; j < 4; j++) {
                gload16(ksrc + (size_t)j * 8 * QKB_LD, &Ks[nxt][(w * 32 + j * 8) * 64]);
                gload16(vsrc0 + (size_t)(j * 4) * VTB_LD + (vColSrc ^ ((j & 1) << 5)),
                        &Vs[nxt][(w * 16 + j * 4) * 128]);
            }
        }

        // ---- QK^T (S^T tile [128 kv][16 q] per wave) ----
        f32x4 s[8];
        __builtin_amdgcn_s_setprio(1);
#pragma unroll
        for (int kg = 0; kg < 8; kg++) {
            const f16* krow = &Ks[cur][(kg * 16 + lr) * 64];
            f16x8 ka0 = *(const f16x8*)(krow + kOffA);
            f16x8 ka1 = *(const f16x8*)(krow + (kOffA ^ 32));
            f32x4 z = {};
            z = __builtin_amdgcn_mfma_f32_16x16x32_f16(ka0, qf0, z, 0, 0, 0);
            s[kg] = __builtin_amdgcn_mfma_f32_16x16x32_f16(ka1, qf1, z, 0, 0, 0);
        }
        __builtin_amdgcn_s_setprio(0);

        // ---- online softmax ----
        float mx = -INFINITY;
#pragma unroll
        for (int kg = 0; kg < 8; kg++)
#pragma unroll
            for (int r = 0; r < 4; r++)
                mx = fmaxf(mx, s[kg][r]);
        mx = fmaxf(mx, __shfl_xor(mx, 16, 64));
        mx = fmaxf(mx, __shfl_xor(mx, 32, 64));
        float mn = fmaxf(m, mx);
        float alpha = __builtin_amdgcn_exp2f((m - mn) * CEXP);
        m = mn;
        float rs = 0.f;
        f16x4 pf[8];
#pragma unroll
        for (int kg = 0; kg < 8; kg++)
#pragma unroll
            for (int r = 0; r < 4; r++) {
                float p = __builtin_amdgcn_exp2f((s[kg][r] - mn) * CEXP);
                rs += p;
                pf[kg][r] = (f16)p;
            }
        rs += __shfl_xor(rs, 16, 64);
        rs += __shfl_xor(rs, 32, 64);
        l = l * alpha + rs;
#pragma unroll
        for (int dg = 0; dg < 4; dg++)
#pragma unroll
            for (int r = 0; r < 4; r++)
                acc[dg][r] *= alpha;

        // ---- PV ----
        __builtin_amdgcn_s_setprio(1);
#pragma unroll
        for (int kg = 0; kg < 8; kg++)
#pragma unroll
            for (int dg = 0; dg < 4; dg++) {
                f16x4 vf = *(const f16x4*)(&Vs[cur][(dg * 16 + lr) * 128 + (vOffL ^ (kg << 4))]);
                acc[dg] = __builtin_amdgcn_mfma_f32_16x16x16f16(vf, pf[kg], acc[dg], 0, 0, 0);
            }
        __builtin_amdgcn_s_setprio(0);

        __syncthreads();  // drains vmcnt(0): next buffer complete, cur reusable
    }

    float inv = 1.f / l;
#pragma unroll
    for (int dg = 0; dg < 4; dg++) {
        f16x4 ov;
#pragma unroll
        for (int r = 0; r < 4; r++) ov[r] = (f16)(acc[dg][r] * inv);
        *(f16x4*)(ao + (size_t)(b * 2048 + q0 + lr) * 512 + h * 64 + dg * 16 + lg * 4) = ov;
    }
}

extern "C" void kernel_launch(void* const* d_in, const int* in_sizes, int n_in,
                              void* d_out, int out_size, void* d_ws, size_t ws_size,
                              hipStream_t stream) {
    const float* x   = (const float*)d_in[0];
    const float* Wq  = (const float*)d_in[1];
    const float* Wkv = (const float*)d_in[2];
    const float* Wo  = (const float*)d_in[3];
    const float* bo  = (const float*)d_in[4];
    float* out = (float*)d_out;

    f16* xb    = (f16*)d_ws;                  // [4096][1024]
    f16* wqkvT = xb + 4096 * 1024;            // [1536][1024]
    f16* woT   = wqkvT + 1536 * 1024;         // [1024][512]
    f16* qkb   = woT + 1024 * 512;            // [4096][QKB_LD]  (Q | K, padded)
    f16* vtb   = qkb + 4096 * QKB_LD;         // [16][64][VTB_LD] V^T (padded)
    f16* ao    = vtb + 16 * 64 * VTB_LD;      // [4096][512]

    conv_f32_f16_k<<<2048, 256, 0, stream>>>(x, xb);
    transpose_conv_k<<<dim3(16, 32), 256, 0, stream>>>(Wq, wqkvT, 512, 1024, 0);
    transpose_conv_k<<<dim3(32, 32), 256, 0, stream>>>(Wkv, wqkvT, 1024, 1024, 512);
    transpose_conv_k<<<dim3(32, 16), 256, 0, stream>>>(Wo, woT, 1024, 512, 0);

    gemm128_k<0><<<32 * 12, 256, 0, stream>>>(xb, wqkvT, qkb, vtb, nullptr, nullptr, 1024, 12);
    attn_k<<<512, 256, 0, stream>>>(qkb, vtb, ao);
    gemm128_k<1><<<32 * 8, 256, 0, stream>>>(ao, woT, nullptr, nullptr, out, bo, 512, 8);
}